// Round 5
// baseline (1530.216 us; speedup 1.0000x reference)
//
#include <hip/hip_runtime.h>

#define NN 200000
#define NE 5000000
#define DIN 128
#define HID 16
#define DOUT 2
#define NB 782          // ceil(NN/256) dst-buckets of 256 nodes
#define CH_SHIFT 14     // src chunks of 16384 nodes (1 MB of xs @ HID=16)
#define NCH 13          // ceil(NN / 16384)
#define NK (NB * NCH)   // 10166 sort keys
#define PB 128          // partition grid blocks
#define PT 512          // partition block threads

static_assert((NN + 255) / 256 == NB, "bucket count");
static_assert(((NN - 1) >> CH_SHIFT) + 1 == NCH, "chunk count");

// ---------------- edge partition: counting sort by (dst>>8, src>>14) ----------------

__global__ __launch_bounds__(PT) void hist_pass(const int* __restrict__ src,
                                                const int* __restrict__ dst,
                                                int* __restrict__ blockHist) {
    __shared__ int h[NK];  // 40.7 KB
    for (int k = threadIdx.x; k < NK; k += PT) h[k] = 0;
    __syncthreads();
    for (int i = blockIdx.x * PT + threadIdx.x; i < NE; i += PB * PT) {
        int key = (dst[i] >> 8) * NCH + (src[i] >> CH_SHIFT);
        atomicAdd(&h[key], 1);
    }
    __syncthreads();
    // layout blockHist[b*NK + k]: contiguous per block -> coalesced writes
    for (int k = threadIdx.x; k < NK; k += PT)
        blockHist[(size_t)blockIdx.x * NK + k] = h[k];
}

__global__ __launch_bounds__(1024) void scan_pass(int* __restrict__ blockHist,
                                                  int* __restrict__ bucketStart) {
    __shared__ int tot[NK];     // 40.7 KB
    __shared__ int psum[1024];  // 4 KB
    int t = threadIdx.x;
    // phase 1: per-key totals; strided k -> wave reads 256B coalesced per b
    for (int k = t; k < NK; k += 1024) {
        int s = 0;
        for (int b = 0; b < PB; ++b) s += blockHist[(size_t)b * NK + k];
        tot[k] = s;
    }
    __syncthreads();
    // phase 2: two-level exclusive scan over keys (order 0..NK-1)
    const int KPT = (NK + 1023) / 1024;  // 10
    int k0 = t * KPT, k1 = (k0 + KPT < NK) ? k0 + KPT : NK;
    int s = 0;
    for (int k = k0; k < k1; ++k) s += tot[k];
    psum[t] = s;
    __syncthreads();
    if (t == 0) {
        int car = 0;
        for (int i = 0; i < 1024; ++i) { int v = psum[i]; psum[i] = car; car += v; }
    }
    __syncthreads();
    {
        int run = psum[t];
        for (int k = k0; k < k1; ++k) { int v = tot[k]; tot[k] = run; run += v; }
    }
    __syncthreads();
    // phase 3: per-(key, block) exclusive offsets in block order
    for (int k = t; k < NK; k += 1024) {
        int r = tot[k];
        for (int b = 0; b < PB; ++b) {
            size_t idx = (size_t)b * NK + k;
            int v = blockHist[idx];
            blockHist[idx] = r;
            r += v;
        }
    }
    // per-dst-bucket ranges for the agg kernels
    for (int k = t; k < NK; k += 1024)
        if (k % NCH == 0) bucketStart[k / NCH] = tot[k];
    if (t == 0) bucketStart[NB] = NE;
}

__global__ __launch_bounds__(PT) void scatter_pass(const int* __restrict__ src,
                                                   const int* __restrict__ dst,
                                                   const int* __restrict__ blockHist,
                                                   unsigned* __restrict__ pedge) {
    __shared__ int cur[NK];  // 40.7 KB
    for (int k = threadIdx.x; k < NK; k += PT)
        cur[k] = blockHist[(size_t)blockIdx.x * NK + k];
    __syncthreads();
    // MUST traverse edges in the same per-block order as hist_pass
    for (int i = blockIdx.x * PT + threadIdx.x; i < NE; i += PB * PT) {
        int sv = src[i], dv = dst[i];
        int key = (dv >> 8) * NCH + (sv >> CH_SHIFT);
        int pos = atomicAdd(&cur[key], 1);  // LDS atomic only
        pedge[pos] = ((unsigned)sv << 8) | (unsigned)(dv & 255);
    }
}

__global__ __launch_bounds__(256) void deg_dis(const unsigned* __restrict__ pedge,
                                               const int* __restrict__ bucketStart,
                                               float* __restrict__ dis) {
    __shared__ int cnt[256];
    int t = threadIdx.x;
    cnt[t] = 1;  // self loop
    __syncthreads();
    int e0 = bucketStart[blockIdx.x], e1 = bucketStart[blockIdx.x + 1];
    for (int e = e0 + t; e < e1; e += 256) atomicAdd(&cnt[pedge[e] & 255u], 1);
    __syncthreads();
    int node = (blockIdx.x << 8) + t;
    if (node < NN) dis[node] = rsqrtf((float)cnt[t]);
}

// ---------------- dense GEMMs, epilogue-scaled by dis[row] ----------------

__global__ __launch_bounds__(256) void gemm_x_w1(const float* __restrict__ x,
                                                 const float* __restrict__ W,
                                                 const float* __restrict__ dis,
                                                 float* __restrict__ out) {
    __shared__ float w[DIN * HID];
    for (int t = threadIdx.x; t < DIN * HID; t += 256) w[t] = W[t];
    __syncthreads();
    int row = blockIdx.x * 16 + (threadIdx.x >> 4);
    int c = threadIdx.x & 15;
    if (row >= NN) return;
    const float4* xr = reinterpret_cast<const float4*>(x + (size_t)row * DIN);
    float acc = 0.f;
#pragma unroll
    for (int k4 = 0; k4 < DIN / 4; ++k4) {
        float4 v = xr[k4];
        acc += v.x * w[(4 * k4 + 0) * HID + c] + v.y * w[(4 * k4 + 1) * HID + c]
             + v.z * w[(4 * k4 + 2) * HID + c] + v.w * w[(4 * k4 + 3) * HID + c];
    }
    out[row * HID + c] = acc * dis[row];
}

__global__ __launch_bounds__(256) void gemm_h_w16(const float* __restrict__ h,
                                                  const float* __restrict__ W,
                                                  const float* __restrict__ dis,
                                                  float* __restrict__ out) {
    __shared__ float w[HID * HID];
    if (threadIdx.x < HID * HID) w[threadIdx.x] = W[threadIdx.x];
    __syncthreads();
    int row = blockIdx.x * 16 + (threadIdx.x >> 4);
    int c = threadIdx.x & 15;
    if (row >= NN) return;
    const float4* hr = reinterpret_cast<const float4*>(h + (size_t)row * HID);
    float acc = 0.f;
#pragma unroll
    for (int k4 = 0; k4 < HID / 4; ++k4) {
        float4 v = hr[k4];
        acc += v.x * w[(4 * k4 + 0) * HID + c] + v.y * w[(4 * k4 + 1) * HID + c]
             + v.z * w[(4 * k4 + 2) * HID + c] + v.w * w[(4 * k4 + 3) * HID + c];
    }
    out[row * HID + c] = acc * dis[row];
}

__global__ __launch_bounds__(256) void gemm_h_w2(const float* __restrict__ h,
                                                 const float* __restrict__ W,
                                                 const float* __restrict__ dis,
                                                 float* __restrict__ out) {
    int t = blockIdx.x * 256 + threadIdx.x;
    int row = t >> 1;
    int c = t & 1;
    if (row >= NN) return;
    const float* hr = h + (size_t)row * HID;
    float acc = 0.f;
#pragma unroll
    for (int k = 0; k < HID; ++k) acc += hr[k] * W[k * DOUT + c];
    out[row * DOUT + c] = acc * dis[row];
}

// ---------------- bucket-local aggregation (LDS atomics only) ----------------

__global__ __launch_bounds__(1024) void agg16(const unsigned* __restrict__ pedge,
                                              const int* __restrict__ bucketStart,
                                              const float* __restrict__ dis,
                                              const float* __restrict__ xs,
                                              const float* __restrict__ bias, int relu,
                                              float* __restrict__ out) {
    __shared__ float acc[256 * HID];  // 16 KB
    __shared__ float dl[256];
    int t = threadIdx.x;
    int base = blockIdx.x << 8;
    if (t < 256) {
        int node = base + t;
        dl[t] = (node < NN) ? dis[node] : 0.f;
    }
    __syncthreads();
    for (int i = t; i < 256 * HID; i += 1024) {  // self-loop init: xs[node]*dis[node]
        int gi = (base << 4) + i;
        acc[i] = (gi < NN * HID) ? xs[gi] * dl[i >> 4] : 0.f;
    }
    __syncthreads();
    int e0 = bucketStart[blockIdx.x], e1 = bucketStart[blockIdx.x + 1];
    int c = t & 15;
    const int NS = 64;  // edge streams per block
    int e = e0 + (t >> 4);
    for (; e + 3 * NS < e1; e += 4 * NS) {
        unsigned p0 = pedge[e];
        unsigned p1 = pedge[e + NS];
        unsigned p2 = pedge[e + 2 * NS];
        unsigned p3 = pedge[e + 3 * NS];
        float v0 = xs[((p0 >> 8) << 4) + c];
        float v1 = xs[((p1 >> 8) << 4) + c];
        float v2 = xs[((p2 >> 8) << 4) + c];
        float v3 = xs[((p3 >> 8) << 4) + c];
        int d0 = p0 & 255u, d1 = p1 & 255u, d2 = p2 & 255u, d3 = p3 & 255u;
        atomicAdd(&acc[(d0 << 4) + c], v0 * dl[d0]);
        atomicAdd(&acc[(d1 << 4) + c], v1 * dl[d1]);
        atomicAdd(&acc[(d2 << 4) + c], v2 * dl[d2]);
        atomicAdd(&acc[(d3 << 4) + c], v3 * dl[d3]);
    }
    for (; e < e1; e += NS) {
        unsigned p = pedge[e];
        int d = p & 255u;
        atomicAdd(&acc[(d << 4) + c], xs[((p >> 8) << 4) + c] * dl[d]);
    }
    __syncthreads();
    for (int i = t; i < 256 * HID; i += 1024) {
        int gi = (base << 4) + i;
        if (gi < NN * HID) {
            float v = acc[i] + bias[i & 15];
            out[gi] = relu ? fmaxf(v, 0.f) : v;
        }
    }
}

__global__ __launch_bounds__(1024) void agg2_lsm(const unsigned* __restrict__ pedge,
                                                 const int* __restrict__ bucketStart,
                                                 const float* __restrict__ dis,
                                                 const float* __restrict__ xs,
                                                 const float* __restrict__ bias,
                                                 float* __restrict__ out) {
    __shared__ float acc[256 * DOUT];
    __shared__ float dl[256];
    int t = threadIdx.x;
    int base = blockIdx.x << 8;
    if (t < 256) {
        int node = base + t;
        float d0 = (node < NN) ? dis[node] : 0.f;
        dl[t] = d0;
        if (node < NN) {
            float2 v = reinterpret_cast<const float2*>(xs)[node];
            acc[t * 2 + 0] = v.x * d0;
            acc[t * 2 + 1] = v.y * d0;
        } else {
            acc[t * 2 + 0] = 0.f;
            acc[t * 2 + 1] = 0.f;
        }
    }
    __syncthreads();
    int e0 = bucketStart[blockIdx.x], e1 = bucketStart[blockIdx.x + 1];
    int c = t & 1;
    const int NS = 512;
    int e = e0 + (t >> 1);
    for (; e + 3 * NS < e1; e += 4 * NS) {
        unsigned p0 = pedge[e];
        unsigned p1 = pedge[e + NS];
        unsigned p2 = pedge[e + 2 * NS];
        unsigned p3 = pedge[e + 3 * NS];
        float v0 = xs[(p0 >> 8) * 2 + c];
        float v1 = xs[(p1 >> 8) * 2 + c];
        float v2 = xs[(p2 >> 8) * 2 + c];
        float v3 = xs[(p3 >> 8) * 2 + c];
        int d0 = p0 & 255u, d1 = p1 & 255u, d2 = p2 & 255u, d3 = p3 & 255u;
        atomicAdd(&acc[d0 * 2 + c], v0 * dl[d0]);
        atomicAdd(&acc[d1 * 2 + c], v1 * dl[d1]);
        atomicAdd(&acc[d2 * 2 + c], v2 * dl[d2]);
        atomicAdd(&acc[d3 * 2 + c], v3 * dl[d3]);
    }
    for (; e < e1; e += NS) {
        unsigned p = pedge[e];
        int d = p & 255u;
        atomicAdd(&acc[d * 2 + c], xs[(p >> 8) * 2 + c] * dl[d]);
    }
    __syncthreads();
    if (t < 256) {
        int node = base + t;
        if (node < NN) {
            float v0 = acc[t * 2 + 0] + bias[0];
            float v1 = acc[t * 2 + 1] + bias[1];
            float m = fmaxf(v0, v1);
            float lse = m + logf(__expf(v0 - m) + __expf(v1 - m));
            reinterpret_cast<float2*>(out)[node] = make_float2(v0 - lse, v1 - lse);
        }
    }
}

// ---------------- launch ----------------

extern "C" void kernel_launch(void* const* d_in, const int* in_sizes, int n_in,
                              void* d_out, int out_size, void* d_ws, size_t ws_size,
                              hipStream_t stream) {
    const float* x = (const float*)d_in[0];
    const int* ei = (const int*)d_in[1];
    const float* W1 = (const float*)d_in[2];
    const float* b1 = (const float*)d_in[3];
    const float* W3 = (const float*)d_in[4];
    const float* b3 = (const float*)d_in[5];
    const float* W2 = (const float*)d_in[6];
    const float* b2 = (const float*)d_in[7];
    float* out = (float*)d_out;

    const int* src = ei;       // edge_index[0]
    const int* dst = ei + NE;  // edge_index[1]

    // workspace layout (~51.7 MB)
    char* ws = (char*)d_ws;
    unsigned* pedge = (unsigned*)ws;                      // NE           (20 MB)
    int* blockHist = (int*)(ws + sizeof(unsigned) * NE);  // PB*NK        (5.2 MB)
    int* bucketStart = blockHist + (size_t)PB * NK;       // NB+1
    float* dis = (float*)(bucketStart + NB + 1);          // NN
    float* bufA = dis + NN;                               // NN*HID       (12.8 MB)
    float* bufB = bufA + NN * HID;                        // NN*HID       (12.8 MB)

    const int B = 256;
    auto cdiv = [](long long a, long long b) { return (int)((a + b - 1) / b); };

    // partition + normalization
    hist_pass<<<PB, PT, 0, stream>>>(src, dst, blockHist);
    scan_pass<<<1, 1024, 0, stream>>>(blockHist, bucketStart);
    scatter_pass<<<PB, PT, 0, stream>>>(src, dst, blockHist, pedge);
    deg_dis<<<NB, B, 0, stream>>>(pedge, bucketStart, dis);

    // conv1
    gemm_x_w1<<<cdiv(NN, 16), B, 0, stream>>>(x, W1, dis, bufA);
    agg16<<<NB, 1024, 0, stream>>>(pedge, bucketStart, dis, bufA, b1, 1, bufB);

    // conv3
    gemm_h_w16<<<cdiv(NN, 16), B, 0, stream>>>(bufB, W3, dis, bufA);
    agg16<<<NB, 1024, 0, stream>>>(pedge, bucketStart, dis, bufA, b3, 1, bufB);

    // conv2 + log_softmax
    gemm_h_w2<<<cdiv((long long)NN * DOUT, B), B, 0, stream>>>(bufB, W2, dis, bufA);
    agg2_lsm<<<NB, 1024, 0, stream>>>(pedge, bucketStart, dis, bufA, b2, out);
}

// Round 6
// 1415.523 us; speedup vs baseline: 1.0810x; 1.0810x over previous
//
#include <hip/hip_runtime.h>

#define NN 200000
#define NE 5000000
#define DIN 128
#define HID 16
#define DOUT 2
#define BSH 9            // dst-buckets of 512 nodes
#define BSZ 512
#define NB 391           // ceil(NN/512)
#define CH_SHIFT 14      // src chunks of 16384 nodes (1 MB of xs @ HID=16)
#define NCH 13           // ceil(NN / 16384)
#define NK (NB * NCH)    // 5083 sort keys
#define PB 128           // partition grid blocks
#define PT 512           // partition block threads

static_assert((NN + BSZ - 1) / BSZ == NB, "bucket count");
static_assert(((NN - 1) >> CH_SHIFT) + 1 == NCH, "chunk count");

// ---------------- edge partition: counting sort by (dst>>9, src>>14) ----------------

__global__ __launch_bounds__(PT) void hist_pass(const int* __restrict__ src,
                                                const int* __restrict__ dst,
                                                int* __restrict__ blockHist) {
    __shared__ int h[NK];  // 20.3 KB
    for (int k = threadIdx.x; k < NK; k += PT) h[k] = 0;
    __syncthreads();
    for (int i = blockIdx.x * PT + threadIdx.x; i < NE; i += PB * PT) {
        int key = (dst[i] >> BSH) * NCH + (src[i] >> CH_SHIFT);
        atomicAdd(&h[key], 1);
    }
    __syncthreads();
    for (int k = threadIdx.x; k < NK; k += PT)
        blockHist[(size_t)blockIdx.x * NK + k] = h[k];
}

__global__ __launch_bounds__(1024) void scan_pass(int* __restrict__ blockHist,
                                                  int* __restrict__ bucketStart) {
    __shared__ int tot[NK];     // 20.3 KB
    __shared__ int psum[1024];  // 4 KB
    int t = threadIdx.x;
    for (int k = t; k < NK; k += 1024) {
        int s = 0;
        for (int b = 0; b < PB; ++b) s += blockHist[(size_t)b * NK + k];
        tot[k] = s;
    }
    __syncthreads();
    const int KPT = (NK + 1023) / 1024;  // 5
    int k0 = t * KPT, k1 = (k0 + KPT < NK) ? k0 + KPT : NK;
    if (k0 > NK) k0 = NK;
    int s = 0;
    for (int k = k0; k < k1; ++k) s += tot[k];
    psum[t] = s;
    __syncthreads();
    if (t == 0) {
        int car = 0;
        for (int i = 0; i < 1024; ++i) { int v = psum[i]; psum[i] = car; car += v; }
    }
    __syncthreads();
    {
        int run = psum[t];
        for (int k = k0; k < k1; ++k) { int v = tot[k]; tot[k] = run; run += v; }
    }
    __syncthreads();
    for (int k = t; k < NK; k += 1024) {
        int r = tot[k];
        for (int b = 0; b < PB; ++b) {
            size_t idx = (size_t)b * NK + k;
            int v = blockHist[idx];
            blockHist[idx] = r;
            r += v;
        }
    }
    for (int k = t; k < NK; k += 1024)
        if (k % NCH == 0) bucketStart[k / NCH] = tot[k];
    if (t == 0) bucketStart[NB] = NE;
}

__global__ __launch_bounds__(PT) void scatter_pass(const int* __restrict__ src,
                                                   const int* __restrict__ dst,
                                                   const int* __restrict__ blockHist,
                                                   unsigned* __restrict__ pedge) {
    __shared__ int cur[NK];  // 20.3 KB
    for (int k = threadIdx.x; k < NK; k += PT)
        cur[k] = blockHist[(size_t)blockIdx.x * NK + k];
    __syncthreads();
    for (int i = blockIdx.x * PT + threadIdx.x; i < NE; i += PB * PT) {
        int sv = src[i], dv = dst[i];
        int key = (dv >> BSH) * NCH + (sv >> CH_SHIFT);
        int pos = atomicAdd(&cur[key], 1);  // LDS atomic only
        pedge[pos] = ((unsigned)sv << BSH) | (unsigned)(dv & (BSZ - 1));
    }
}

__global__ __launch_bounds__(BSZ) void deg_dis(const unsigned* __restrict__ pedge,
                                               const int* __restrict__ bucketStart,
                                               float* __restrict__ dis) {
    __shared__ int cnt[BSZ];
    int t = threadIdx.x;
    cnt[t] = 1;  // self loop
    __syncthreads();
    int e0 = bucketStart[blockIdx.x], e1 = bucketStart[blockIdx.x + 1];
    for (int e = e0 + t; e < e1; e += BSZ) atomicAdd(&cnt[pedge[e] & (BSZ - 1u)], 1);
    __syncthreads();
    int node = (blockIdx.x << BSH) + t;
    if (node < NN) dis[node] = rsqrtf((float)cnt[t]);
}

// ---------------- dense GEMMs, epilogue-scaled by dis[row] ----------------

__global__ __launch_bounds__(256) void gemm_x_w1(const float* __restrict__ x,
                                                 const float* __restrict__ W,
                                                 const float* __restrict__ dis,
                                                 float* __restrict__ out) {
    __shared__ float w[DIN * HID];
    for (int t = threadIdx.x; t < DIN * HID; t += 256) w[t] = W[t];
    __syncthreads();
    int row = blockIdx.x * 16 + (threadIdx.x >> 4);
    int c = threadIdx.x & 15;
    if (row >= NN) return;
    const float4* xr = reinterpret_cast<const float4*>(x + (size_t)row * DIN);
    float acc = 0.f;
#pragma unroll
    for (int k4 = 0; k4 < DIN / 4; ++k4) {
        float4 v = xr[k4];
        acc += v.x * w[(4 * k4 + 0) * HID + c] + v.y * w[(4 * k4 + 1) * HID + c]
             + v.z * w[(4 * k4 + 2) * HID + c] + v.w * w[(4 * k4 + 3) * HID + c];
    }
    out[row * HID + c] = acc * dis[row];
}

__global__ __launch_bounds__(256) void gemm_h_w16(const float* __restrict__ h,
                                                  const float* __restrict__ W,
                                                  const float* __restrict__ dis,
                                                  float* __restrict__ out) {
    __shared__ float w[HID * HID];
    if (threadIdx.x < HID * HID) w[threadIdx.x] = W[threadIdx.x];
    __syncthreads();
    int row = blockIdx.x * 16 + (threadIdx.x >> 4);
    int c = threadIdx.x & 15;
    if (row >= NN) return;
    const float4* hr = reinterpret_cast<const float4*>(h + (size_t)row * HID);
    float acc = 0.f;
#pragma unroll
    for (int k4 = 0; k4 < HID / 4; ++k4) {
        float4 v = hr[k4];
        acc += v.x * w[(4 * k4 + 0) * HID + c] + v.y * w[(4 * k4 + 1) * HID + c]
             + v.z * w[(4 * k4 + 2) * HID + c] + v.w * w[(4 * k4 + 3) * HID + c];
    }
    out[row * HID + c] = acc * dis[row];
}

__global__ __launch_bounds__(256) void gemm_h_w2(const float* __restrict__ h,
                                                 const float* __restrict__ W,
                                                 const float* __restrict__ dis,
                                                 float* __restrict__ out) {
    int t = blockIdx.x * 256 + threadIdx.x;
    int row = t >> 1;
    int c = t & 1;
    if (row >= NN) return;
    const float* hr = h + (size_t)row * HID;
    float acc = 0.f;
#pragma unroll
    for (int k = 0; k < HID; ++k) acc += hr[k] * W[k * DOUT + c];
    out[row * DOUT + c] = acc * dis[row];
}

// ---------------- bucket-local aggregation (391 blocks, ALL resident, lock-step chunks) ----------------

__global__ __launch_bounds__(1024) void agg16(const unsigned* __restrict__ pedge,
                                              const int* __restrict__ bucketStart,
                                              const float* __restrict__ dis,
                                              const float* __restrict__ xs,
                                              const float* __restrict__ bias, int relu,
                                              float* __restrict__ out) {
    __shared__ float acc[BSZ * HID];  // 32 KB
    __shared__ float dl[BSZ];         // 2 KB
    int t = threadIdx.x;
    int base = blockIdx.x << BSH;
    if (t < BSZ) {
        int node = base + t;
        dl[t] = (node < NN) ? dis[node] : 0.f;
    }
    __syncthreads();
    for (int i = t; i < BSZ * HID; i += 1024) {  // self-loop init: xs[node]*dis[node]
        int gi = (base << 4) + i;
        acc[i] = (gi < NN * HID) ? xs[gi] * dl[i >> 4] : 0.f;
    }
    __syncthreads();
    int e0 = bucketStart[blockIdx.x], e1 = bucketStart[blockIdx.x + 1];
    int c = t & 15;
    const int NS = 64;  // edge streams per block
    int e = e0 + (t >> 4);
    for (; e + 3 * NS < e1; e += 4 * NS) {
        unsigned p0 = pedge[e];
        unsigned p1 = pedge[e + NS];
        unsigned p2 = pedge[e + 2 * NS];
        unsigned p3 = pedge[e + 3 * NS];
        float v0 = xs[((p0 >> BSH) << 4) + c];
        float v1 = xs[((p1 >> BSH) << 4) + c];
        float v2 = xs[((p2 >> BSH) << 4) + c];
        float v3 = xs[((p3 >> BSH) << 4) + c];
        int d0 = p0 & (BSZ - 1u), d1 = p1 & (BSZ - 1u);
        int d2 = p2 & (BSZ - 1u), d3 = p3 & (BSZ - 1u);
        atomicAdd(&acc[(d0 << 4) + c], v0 * dl[d0]);
        atomicAdd(&acc[(d1 << 4) + c], v1 * dl[d1]);
        atomicAdd(&acc[(d2 << 4) + c], v2 * dl[d2]);
        atomicAdd(&acc[(d3 << 4) + c], v3 * dl[d3]);
    }
    for (; e < e1; e += NS) {
        unsigned p = pedge[e];
        int d = p & (BSZ - 1u);
        atomicAdd(&acc[(d << 4) + c], xs[((p >> BSH) << 4) + c] * dl[d]);
    }
    __syncthreads();
    for (int i = t; i < BSZ * HID; i += 1024) {
        int gi = (base << 4) + i;
        if (gi < NN * HID) {
            float v = acc[i] + bias[i & 15];
            out[gi] = relu ? fmaxf(v, 0.f) : v;
        }
    }
}

__global__ __launch_bounds__(1024) void agg2_lsm(const unsigned* __restrict__ pedge,
                                                 const int* __restrict__ bucketStart,
                                                 const float* __restrict__ dis,
                                                 const float* __restrict__ xs,
                                                 const float* __restrict__ bias,
                                                 float* __restrict__ out) {
    __shared__ float acc[BSZ * DOUT];  // 4 KB
    __shared__ float dl[BSZ];
    int t = threadIdx.x;
    int base = blockIdx.x << BSH;
    if (t < BSZ) {
        int node = base + t;
        float d0 = (node < NN) ? dis[node] : 0.f;
        dl[t] = d0;
        if (node < NN) {
            float2 v = reinterpret_cast<const float2*>(xs)[node];
            acc[t * 2 + 0] = v.x * d0;
            acc[t * 2 + 1] = v.y * d0;
        } else {
            acc[t * 2 + 0] = 0.f;
            acc[t * 2 + 1] = 0.f;
        }
    }
    __syncthreads();
    int e0 = bucketStart[blockIdx.x], e1 = bucketStart[blockIdx.x + 1];
    int c = t & 1;
    const int NS = 512;
    int e = e0 + (t >> 1);
    for (; e + 3 * NS < e1; e += 4 * NS) {
        unsigned p0 = pedge[e];
        unsigned p1 = pedge[e + NS];
        unsigned p2 = pedge[e + 2 * NS];
        unsigned p3 = pedge[e + 3 * NS];
        float v0 = xs[(p0 >> BSH) * 2 + c];
        float v1 = xs[(p1 >> BSH) * 2 + c];
        float v2 = xs[(p2 >> BSH) * 2 + c];
        float v3 = xs[(p3 >> BSH) * 2 + c];
        int d0 = p0 & (BSZ - 1u), d1 = p1 & (BSZ - 1u);
        int d2 = p2 & (BSZ - 1u), d3 = p3 & (BSZ - 1u);
        atomicAdd(&acc[d0 * 2 + c], v0 * dl[d0]);
        atomicAdd(&acc[d1 * 2 + c], v1 * dl[d1]);
        atomicAdd(&acc[d2 * 2 + c], v2 * dl[d2]);
        atomicAdd(&acc[d3 * 2 + c], v3 * dl[d3]);
    }
    for (; e < e1; e += NS) {
        unsigned p = pedge[e];
        int d = p & (BSZ - 1u);
        atomicAdd(&acc[d * 2 + c], xs[(p >> BSH) * 2 + c] * dl[d]);
    }
    __syncthreads();
    if (t < BSZ) {
        int node = base + t;
        if (node < NN) {
            float v0 = acc[t * 2 + 0] + bias[0];
            float v1 = acc[t * 2 + 1] + bias[1];
            float m = fmaxf(v0, v1);
            float lse = m + logf(__expf(v0 - m) + __expf(v1 - m));
            reinterpret_cast<float2*>(out)[node] = make_float2(v0 - lse, v1 - lse);
        }
    }
}

// ---------------- launch ----------------

extern "C" void kernel_launch(void* const* d_in, const int* in_sizes, int n_in,
                              void* d_out, int out_size, void* d_ws, size_t ws_size,
                              hipStream_t stream) {
    const float* x = (const float*)d_in[0];
    const int* ei = (const int*)d_in[1];
    const float* W1 = (const float*)d_in[2];
    const float* b1 = (const float*)d_in[3];
    const float* W3 = (const float*)d_in[4];
    const float* b3 = (const float*)d_in[5];
    const float* W2 = (const float*)d_in[6];
    const float* b2 = (const float*)d_in[7];
    float* out = (float*)d_out;

    const int* src = ei;       // edge_index[0]
    const int* dst = ei + NE;  // edge_index[1]

    // workspace layout (~49 MB)
    char* ws = (char*)d_ws;
    unsigned* pedge = (unsigned*)ws;                      // NE          (20 MB)
    int* blockHist = (int*)(ws + sizeof(unsigned) * NE);  // PB*NK       (2.6 MB)
    int* bucketStart = blockHist + (size_t)PB * NK;       // NB+1
    float* dis = (float*)(bucketStart + NB + 1);          // NN
    float* bufA = dis + NN;                               // NN*HID      (12.8 MB)
    float* bufB = bufA + NN * HID;                        // NN*HID      (12.8 MB)

    const int B = 256;
    auto cdiv = [](long long a, long long b) { return (int)((a + b - 1) / b); };

    // partition + normalization
    hist_pass<<<PB, PT, 0, stream>>>(src, dst, blockHist);
    scan_pass<<<1, 1024, 0, stream>>>(blockHist, bucketStart);
    scatter_pass<<<PB, PT, 0, stream>>>(src, dst, blockHist, pedge);
    deg_dis<<<NB, BSZ, 0, stream>>>(pedge, bucketStart, dis);

    // conv1
    gemm_x_w1<<<cdiv(NN, 16), B, 0, stream>>>(x, W1, dis, bufA);
    agg16<<<NB, 1024, 0, stream>>>(pedge, bucketStart, dis, bufA, b1, 1, bufB);

    // conv3
    gemm_h_w16<<<cdiv(NN, 16), B, 0, stream>>>(bufB, W3, dis, bufA);
    agg16<<<NB, 1024, 0, stream>>>(pedge, bucketStart, dis, bufA, b3, 1, bufB);

    // conv2 + log_softmax
    gemm_h_w2<<<cdiv((long long)NN * DOUT, B), B, 0, stream>>>(bufB, W2, dis, bufA);
    agg2_lsm<<<NB, 1024, 0, stream>>>(pedge, bucketStart, dis, bufA, b2, out);
}